// Round 9
// baseline (211.473 us; speedup 1.0000x reference)
//
#include <hip/hip_runtime.h>
#include <math.h>

// ---------------------------------------------------------------------------
// RWKV7-ish CausalSelfAttention, MI355X gfx950.
// B=4 T=2048 C=1024 NH=16 HS=64.
// Pipeline: castall v2 (ILP-4) -> bf16 ;
//   GEMM1: 256x128 block, BK=32 DOUBLE-BUFFERED (48KB LDS = same as before,
//          2 blocks/CU), stage(next)->compute(cur)->vmcnt(0)->barrier, XCD
//          swizzle; fused groupnorm/fast-erf -> E ;
//   band_vt rolling chunked scan -> vt ;
//   GEMM2: 128x128 block, BK=64 double-buffered (64KB LDS, 2 blocks/CU),
//          same minimal-pipeline schedule + residual.
// R8/R9 rationale: gemm1 showed ~23% no-issue cycles = per-tile vmcnt(0)
//   drain issued right after the GLL16 batch. Minimal T3 form moves the
//   drain to AFTER the MFMA cluster (prefetch distance 1, vmcnt(0), 2 bufs)
//   with ALL other parameters held at the proven point (same LDS size, same
//   MFMA/barrier, same barrier count, same K order -> bit-identical).
//   R8 bench died at the container level (infra); resubmitting unchanged.
// Workspace: xb 16MB | Wab 6MB | Wpb 2MB | E 48MB | vt 16MB = 88MiB
// ---------------------------------------------------------------------------

typedef __attribute__((ext_vector_type(8))) short short8;     // 8 x bf16 bits
typedef __attribute__((ext_vector_type(4))) float floatx4;

#define GLL16(g, l)                                                            \
    __builtin_amdgcn_global_load_lds(                                          \
        (const __attribute__((address_space(1))) void*)(g),                    \
        (__attribute__((address_space(3))) void*)(l), 16, 0, 0)

#define SYNCV0                                                                 \
    __builtin_amdgcn_sched_barrier(0);                                         \
    asm volatile("s_waitcnt vmcnt(0)" ::: "memory");                           \
    __builtin_amdgcn_s_barrier();                                              \
    __builtin_amdgcn_sched_barrier(0);

static __device__ __forceinline__ unsigned short f2bf(float f) {
    unsigned u = __float_as_uint(f);
    unsigned r = (u + 0x7fffu + ((u >> 16) & 1u)) >> 16;
    return (unsigned short)r;
}
static __device__ __forceinline__ float bflo(unsigned v) { return __uint_as_float(v << 16); }

// Abramowitz-Stegun 7.1.28: |err| <= 3e-7, branch-free.
static __device__ __forceinline__ float erf_fast(float x) {
    float ax = __builtin_fabsf(x);
    float p = fmaf(0.0000430638f, ax, 0.0002765672f);
    p = fmaf(p, ax, 0.0001520143f);
    p = fmaf(p, ax, 0.0092705272f);
    p = fmaf(p, ax, 0.0422820123f);
    p = fmaf(p, ax, 0.0705230784f);
    p = fmaf(p, ax, 1.0f);
    float r = 1.0f / p;
    float r2 = r * r, r4 = r2 * r2, r8 = r4 * r4, r16 = r8 * r8;
    return __builtin_copysignf(1.0f - r16, x);
}

// sum across the 16 lanes of a DPP row, result in every lane of the row.
static __device__ __forceinline__ float sum16(float x) {
    int t;
    t = __builtin_amdgcn_update_dpp(0, __float_as_int(x), 0x128, 0xf, 0xf, false); // row_ror:8
    x += __int_as_float(t);
    t = __builtin_amdgcn_update_dpp(0, __float_as_int(x), 0x124, 0xf, 0xf, false); // row_ror:4
    x += __int_as_float(t);
    t = __builtin_amdgcn_update_dpp(0, __float_as_int(x), 0x122, 0xf, 0xf, false); // row_ror:2
    x += __int_as_float(t);
    t = __builtin_amdgcn_update_dpp(0, __float_as_int(x), 0x121, 0xf, 0xf, false); // row_ror:1
    x += __int_as_float(t);
    return x;
}
// full 64-lane sum, result in every lane.
static __device__ __forceinline__ float sum64_all(float x) {
    x = sum16(x);
    int t = __builtin_amdgcn_ds_swizzle(__float_as_int(x), 0x401F);  // xor 16 (within 32)
    x += __int_as_float(t);
    x += __shfl_xor(x, 32, 64);                                      // xor 32
    return x;
}

// ---------------- fused cast fp32 -> bf16 (x | Wa | Wp, contiguous out) -----
__global__ __launch_bounds__(256) void castall(const float4* __restrict__ x,
                                               const float4* __restrict__ wa,
                                               const float4* __restrict__ wp,
                                               uint2* __restrict__ out) {
    int base = blockIdx.x * 1024 + threadIdx.x;
    #pragma unroll
    for (int k = 0; k < 4; k++) {
        int i = base + k * 256;
        const float4* src;
        int off;
        if (i < 2097152)      { src = x;  off = 0; }
        else if (i < 2883584) { src = wa; off = 2097152; }
        else                  { src = wp; off = 2883584; }
        float4 v = src[i - off];
        uint2 o;
        o.x = (unsigned)f2bf(v.x) | ((unsigned)f2bf(v.y) << 16);
        o.y = (unsigned)f2bf(v.z) | ((unsigned)f2bf(v.w) << 16);
        out[i] = o;
    }
}

// ---------------- GEMM1: qkv = xb @ Wab^T, fused norm+erf -> E --------------
// 256x128 block, 4 waves 2x2, wave tile 128x64 (acc[8][4]). BK=32, dbuf.
// LDS 48KB: A0|A1 (2x16KB) + B0|B1 (2x8KB). Per tile: 6 GLL16 (A4+B2),
// 12 ds_read_b128, 32 MFMA. Swizzle: granule (row r, chunk c) at slot
// (c + (r>>1))&3 -> reads 2-way max (free), staging linear in tid.
// K order: BK=32 tile 2t/2t+1 == old BK=64 tile t half0/half1 -> identical.
__global__ __launch_bounds__(256, 2) void gemm1_qkv_norm(const unsigned short* __restrict__ A,
                                                         const unsigned short* __restrict__ Bm,
                                                         unsigned short* __restrict__ E) {
    __shared__ unsigned short L[24576];        // 48 KB
    unsigned short* A0 = L;                    // 8192 shorts
    unsigned short* A1 = L + 8192;
    unsigned short* B0 = L + 16384;            // 4096 shorts
    unsigned short* B1 = L + 20480;

    const int wg = blockIdx.x;                 // 0..767
    const int swz = (wg & 7) * 96 + (wg >> 3); // bijective, 768 % 8 == 0
    const int bx = swz % 24, by = swz / 24;
    const int M0 = by * 256, N0 = bx * 128;
    const int tid = threadIdx.x;
    const int lane = tid & 63, wav = tid >> 6;
    const int r16 = lane & 15, quad = lane >> 4;
    const int wm = wav >> 1, wn = wav & 1;
    const int m0 = M0 + wm * 128, n0 = N0 + wn * 64;
    const int fa = wm * 128 + r16, fb = wn * 64 + r16;
    const int sA = (quad + (fa >> 1)) & 3;     // read slot (same for all i)
    const int sB = (quad + (fb >> 1)) & 3;
    const int cA = ((tid & 3) - (tid >> 3)) & 3;  // staged global chunk
    const unsigned short* pSA = A  + (size_t)(M0 + (tid >> 2)) * 1024 + cA * 8;
    const unsigned short* pSB = Bm + (size_t)(N0 + (tid >> 2)) * 1024 + cA * 8;

    floatx4 acc[8][4];
    #pragma unroll
    for (int i = 0; i < 8; i++)
        #pragma unroll
        for (int j = 0; j < 4; j++) acc[i][j] = (floatx4)0.0f;

#define G1_ST(KS_, AD_, BD_)                                                   \
    _Pragma("unroll") for (int p = 0; p < 4; p++)                              \
        GLL16(pSA + (size_t)(KS_) * 32 + (size_t)p * 65536,                    \
              (AD_) + p * 2048 + wav * 512);                                   \
    _Pragma("unroll") for (int p = 0; p < 2; p++)                              \
        GLL16(pSB + (size_t)(KS_) * 32 + (size_t)p * 65536,                    \
              (BD_) + p * 2048 + wav * 512);                                   \
    __builtin_amdgcn_sched_barrier(0);

#define G1_CP(AS_, BS_)                                                        \
    {                                                                          \
        short8 af[8], bf[4];                                                   \
        _Pragma("unroll") for (int i = 0; i < 8; i++)                          \
            af[i] = *(const short8*)((AS_) + (fa + i * 16) * 32 + sA * 8);     \
        _Pragma("unroll") for (int j = 0; j < 4; j++)                          \
            bf[j] = *(const short8*)((BS_) + (fb + j * 16) * 32 + sB * 8);     \
        _Pragma("unroll") for (int i = 0; i < 8; i++)                          \
            _Pragma("unroll") for (int j = 0; j < 4; j++)                      \
                acc[i][j] = __builtin_amdgcn_mfma_f32_16x16x32_bf16(           \
                    af[i], bf[j], acc[i][j], 0, 0, 0);                         \
    }

    // prologue: tile 0 -> buf0
    G1_ST(0, A0, B0)
    SYNCV0
    #pragma unroll 1
    for (int kk = 0; kk < 15; kk++) {          // tiles 0..29
        G1_ST(2 * kk + 1, A1, B1)
        G1_CP(A0, B0)
        SYNCV0
        G1_ST(2 * kk + 2, A0, B0)
        G1_CP(A1, B1)
        SYNCV0
    }
    G1_ST(31, A1, B1)                          // tile 30 compute, stage 31
    G1_CP(A0, B0)
    SYNCV0
    G1_CP(A1, B1)                              // tile 31

    // fused per-64-group normalization: this wave's 64-col tile == one (three,h)
    int gcol  = n0 >> 6;            // 0..47
    int three = gcol >> 4, h = gcol & 15;
    #pragma unroll
    for (int i = 0; i < 8; i++) {
        #pragma unroll
        for (int r = 0; r < 4; r++) {
            float s = 0.f, ss = 0.f;
            #pragma unroll
            for (int j = 0; j < 4; j++) { float v = acc[i][j][r]; s += v; ss += v * v; }
            s = sum16(s); ss = sum16(ss);
            float mean = s * (1.0f / 64.0f);
            float var  = (ss - s * s * (1.0f / 64.0f)) * (1.0f / 63.0f);  // ddof=1
            float rstd = rsqrtf(var);
            int rowm = m0 + i * 16 + quad * 4 + r;     // = b*2048 + t
            int bb = rowm >> 11, tt2 = rowm & 2047;
            size_t base = ((((size_t)three * 4 + bb) * 16 + h) * 2048 + tt2) * 64;
            #pragma unroll
            for (int j = 0; j < 4; j++) {
                float v = (acc[i][j][r] - mean) * rstd;
                if (three < 2) v = erf_fast(v);
                E[base + j * 16 + r16] = f2bf(v);
            }
        }
    }
}

// ---------------- GEMM2: out = x + vt @ Wp^T (fp32 out) ---------------------
// 128x128 block, 4 waves 2x2, wave tile 64x64 (acc[4][4]). BK=64, dbuf.
// LDS 64KB: A0|A1 (2x16KB) + B0|B1 (2x16KB). Same minimal-pipeline schedule.
// R1-family 8-chunk swizzle (slot=(c+r)&7), staging linear. XCD swizzle.
__global__ __launch_bounds__(256, 2) void gemm2_proj_add(const unsigned short* __restrict__ A,
                                                         const unsigned short* __restrict__ Bm,
                                                         const float* __restrict__ X,
                                                         float* __restrict__ Out) {
    __shared__ unsigned short L[32768];        // 64 KB
    unsigned short* A0 = L;                    // 8192 shorts each
    unsigned short* A1 = L + 8192;
    unsigned short* B0 = L + 16384;
    unsigned short* B1 = L + 24576;

    const int wg = blockIdx.x;                 // 0..511
    const int swz = (wg & 7) * 64 + (wg >> 3); // bijective, 512 % 8 == 0
    const int bx = swz & 7, by = swz >> 3;
    const int tid = threadIdx.x;
    const int lane = tid & 63, wav = tid >> 6;
    const int r16 = lane & 15, quad = lane >> 4;
    const int M0 = by * 128, N0 = bx * 128;
    const int wm = wav >> 1, wn = wav & 1;
    const int m0 = M0 + wm * 64, n0 = N0 + wn * 64;
    const int rr0 = tid >> 3;                      // 0..31
    const int cc0 = (tid - rr0) & 7;
    const unsigned short* pA0 = A  + (size_t)(M0 + rr0) * 1024 + cc0 * 8;
    const unsigned short* pB0 = Bm + (size_t)(N0 + rr0) * 1024 + cc0 * 8;
    const int fa = wm * 64 + r16, fb = wn * 64 + r16;
    const int swa0 = (quad + fa) & 7, swa1 = (swa0 + 4) & 7;
    const int swb0 = (quad + fb) & 7, swb1 = (swb0 + 4) & 7;

    floatx4 acc[4][4];
    #pragma unroll
    for (int i = 0; i < 4; i++)
        #pragma unroll
        for (int j = 0; j < 4; j++) acc[i][j] = (floatx4)0.0f;

#define G2_ST(KS_, AD_, BD_)                                                   \
    _Pragma("unroll") for (int p = 0; p < 4; p++)                              \
        GLL16(pA0 + (size_t)(KS_) * 64 + (size_t)p * 32768,                    \
              (AD_) + p * 2048 + wav * 512);                                   \
    _Pragma("unroll") for (int p = 0; p < 4; p++)                              \
        GLL16(pB0 + (size_t)(KS_) * 64 + (size_t)p * 32768,                    \
              (BD_) + p * 2048 + wav * 512);                                   \
    __builtin_amdgcn_sched_barrier(0);

#define G2_CP(AS_, BS_)                                                        \
    {                                                                          \
        short8 af[4], bf[4];                                                   \
        _Pragma("unroll") for (int i = 0; i < 4; i++)                          \
            af[i] = *(const short8*)((AS_) + (fa + i * 16) * 64 + swa0 * 8);   \
        _Pragma("unroll") for (int j = 0; j < 4; j++)                          \
            bf[j] = *(const short8*)((BS_) + (fb + j * 16) * 64 + swb0 * 8);   \
        _Pragma("unroll") for (int i = 0; i < 4; i++)                          \
            _Pragma("unroll") for (int j = 0; j < 4; j++)                      \
                acc[i][j] = __builtin_amdgcn_mfma_f32_16x16x32_bf16(           \
                    af[i], bf[j], acc[i][j], 0, 0, 0);                         \
        _Pragma("unroll") for (int i = 0; i < 4; i++)                          \
            af[i] = *(const short8*)((AS_) + (fa + i * 16) * 64 + swa1 * 8);   \
        _Pragma("unroll") for (int j = 0; j < 4; j++)                          \
            bf[j] = *(const short8*)((BS_) + (fb + j * 16) * 64 + swb1 * 8);   \
        _Pragma("unroll") for (int i = 0; i < 4; i++)                          \
            _Pragma("unroll") for (int j = 0; j < 4; j++)                      \
                acc[i][j] = __builtin_amdgcn_mfma_f32_16x16x32_bf16(           \
                    af[i], bf[j], acc[i][j], 0, 0, 0);                         \
    }

    G2_ST(0, A0, B0)
    SYNCV0
    #pragma unroll 1
    for (int kk = 0; kk < 7; kk++) {           // tiles 0..13
        G2_ST(2 * kk + 1, A1, B1)
        G2_CP(A0, B0)
        SYNCV0
        G2_ST(2 * kk + 2, A0, B0)
        G2_CP(A1, B1)
        SYNCV0
    }
    G2_ST(15, A1, B1)                          // tile 14 compute, stage 15
    G2_CP(A0, B0)
    SYNCV0
    G2_CP(A1, B1)                              // tile 15

    #pragma unroll
    for (int i = 0; i < 4; i++)
        #pragma unroll
        for (int j = 0; j < 4; j++)
            #pragma unroll
            for (int r = 0; r < 4; r++) {
                size_t idx = (size_t)(m0 + i * 16 + quad * 4 + r) * 1024 + (n0 + j * 16 + r16);
                Out[idx] = acc[i][j][r] + X[idx];
            }
}

// ---------------- rolling chunked scan -> vt --------------------------------
// Exact recursion carried in registers: sv_t = v_t - G_t * sv_{t-1},
//   G_t = k~_{t-1}.k_t ; vt_t[i] = H0 sv_t[i] + w_i H1 sv_{t-1}[i].
// One wave per (b,h,chunk-of-16): 64 x 128 = 8192 waves = 2048 blocks.
__global__ __launch_bounds__(256) void band_vt(const unsigned short* __restrict__ E,
                                               const float* __restrict__ w,
                                               const float* __restrict__ eta,
                                               unsigned short* __restrict__ vt) {
    const int lane = threadIdx.x & 63;
    const int wav  = threadIdx.x >> 6;
    const int gid  = blockIdx.x * 4 + wav;        // 0..8191
    const int chunk = gid & 127;                  // 128 chunks of 16 t
    const int p     = gid >> 7;                   // (b,h): 0..63
    const int b = p >> 4, h = p & 15;
    const int t0 = chunk * 16;

    const size_t PL = (size_t)4 * 16 * 2048 * 64;               // one "three" plane
    const size_t pbh = ((size_t)b * 16 + h) * (2048 * 64);
    const unsigned short* qb = E + pbh;
    const unsigned short* kb = E + PL + pbh;
    const unsigned short* vb = E + 2 * PL + pbh;

    const float e  = eta[h * 64 + lane];
    const float wi = w[h * 64 + lane];

    // ---- warm-up: rolling kh_{t0-1} and seeded sv_{t0-1} (wave-uniform guards)
    float kh_p, sv_p;
    if (t0 == 0) {
        kh_p = 0.f;
        sv_p = 0.f;
    } else {
        float k1 = bflo(kb[(size_t)(t0 - 1) * 64 + lane]);
        float k2 = bflo(kb[(size_t)(t0 - 2) * 64 + lane]);
        float k3 = bflo(kb[(size_t)(t0 - 3) * 64 + lane]);
        float v1 = bflo(vb[(size_t)(t0 - 1) * 64 + lane]);
        float v2 = bflo(vb[(size_t)(t0 - 2) * 64 + lane]);
        float v3 = bflo(vb[(size_t)(t0 - 3) * 64 + lane]);
        float G1 = sum64_all((k2 * e) * k1);      // G_{t0-1} = k~_{t0-2}.k_{t0-1}
        float G2 = sum64_all((k3 * e) * k2);      // G_{t0-2} = k~_{t0-3}.k_{t0-2}
        sv_p = v1 - G1 * (v2 - G2 * v3);          // sv_{t0-1}, 3-term seed
        kh_p = k1 * e;
    }

    const unsigned short* pq = qb + (size_t)t0 * 64 + lane;
    const unsigned short* pk = kb + (size_t)t0 * 64 + lane;
    const unsigned short* pv = vb + (size_t)t0 * 64 + lane;
    unsigned short* po = vt + ((size_t)b * 2048 + t0) * 1024 + h * 64 + lane;

    #pragma unroll
    for (int tt = 0; tt < 16; tt++) {
        float qt = bflo(pq[tt * 64]);
        float kt = bflo(pk[tt * 64]);
        float vv = bflo(pv[tt * 64]);
        float kh = kt * e;
        float Gt = sum64_all(kh_p * kt);          // k~_{t-1}.k_t
        float H0 = sum64_all(kh * qt);            // k~_t.q_t
        float H1 = sum64_all(kh_p * qt);          // k~_{t-1}.q_t
        float sv = fmaf(-Gt, sv_p, vv);           // sv_t = v_t - G_t sv_{t-1}
        float r  = fmaf(H0, sv, wi * (H1 * sv_p));
        po[(size_t)tt * 1024] = f2bf(r);
        kh_p = kh;
        sv_p = sv;
    }
}

// ---------------------------------------------------------------------------
extern "C" void kernel_launch(void* const* d_in, const int* in_sizes, int n_in,
                              void* d_out, int out_size, void* d_ws, size_t ws_size,
                              hipStream_t stream) {
    const float* x   = (const float*)d_in[0];   // (4,2048,1024)
    const float* Wa  = (const float*)d_in[1];   // (3072,1024)
    const float* Wp  = (const float*)d_in[2];   // (1024,1024)
    const float* w   = (const float*)d_in[3];   // (1024,)
    const float* eta = (const float*)d_in[4];   // (1024,)
    float* out = (float*)d_out;

    char* ws = (char*)d_ws;
    unsigned short* xb  = (unsigned short*)(ws + 0);          // 16777216 B
    unsigned short* Wab = (unsigned short*)(ws + 16777216);   //  6291456 B
    unsigned short* Wpb = (unsigned short*)(ws + 23068672);   //  2097152 B
    unsigned short* E   = (unsigned short*)(ws + 25165824);   // 50331648 B
    unsigned short* vtb = (unsigned short*)(ws + 75497728);   // 16777216 B  -> end 92274944

    castall<<<3072, 256, 0, stream>>>((const float4*)x, (const float4*)Wa,
                                      (const float4*)Wp, (uint2*)xb);

    gemm1_qkv_norm<<<768, 256, 0, stream>>>(xb, Wab, E);
    band_vt<<<2048, 256, 0, stream>>>(E, w, eta, vtb);
    gemm2_proj_add<<<512, 256, 0, stream>>>(vtb, Wpb, x, out);
}

// Round 10
// 199.589 us; speedup vs baseline: 1.0595x; 1.0595x over previous
//
#include <hip/hip_runtime.h>
#include <math.h>

// ---------------------------------------------------------------------------
// RWKV7-ish CausalSelfAttention, MI355X gfx950.
// B=4 T=2048 C=1024 NH=16 HS=64.
// Pipeline: castall v2 (ILP-4) -> bf16 ;
//   GEMM1: 256x128 block, 8 waves x 64x64 wave tiles (acc[4][4] = 64 AGPR),
//          BK=64, 2-barrier GLL16 core, XCD swizzle. Unified-RF insight:
//          old 4-wave core = 84 VGPR + 128 AGPR = 212 regs -> 2 waves/SIMD;
//          8-wave 64x64 = ~124 regs -> 4 waves/SIMD = 16 waves/CU (2x).
//          Same schedule/swizzle/K-order -> bit-identical numerics.
//   band_vt rolling chunked scan -> vt ;
//   GEMM2: 128x128 block, BK=128 double-stage (R7-proven) + residual.
// R2/R3/R5/R9 lesson: ALL manual pipelining variants regress; the compiler-
//   scheduled 2-barrier core + cross-block wave overlap is the structure.
//   The only winning lever on this problem has been occupancy/packing.
// Workspace: xb 16MB | Wab 6MB | Wpb 2MB | E 48MB | vt 16MB = 88MiB
// ---------------------------------------------------------------------------

typedef __attribute__((ext_vector_type(8))) short short8;     // 8 x bf16 bits
typedef __attribute__((ext_vector_type(4))) float floatx4;

#define GLL16(g, l)                                                            \
    __builtin_amdgcn_global_load_lds(                                          \
        (const __attribute__((address_space(1))) void*)(g),                    \
        (__attribute__((address_space(3))) void*)(l), 16, 0, 0)

static __device__ __forceinline__ unsigned short f2bf(float f) {
    unsigned u = __float_as_uint(f);
    unsigned r = (u + 0x7fffu + ((u >> 16) & 1u)) >> 16;
    return (unsigned short)r;
}
static __device__ __forceinline__ float bflo(unsigned v) { return __uint_as_float(v << 16); }

// Abramowitz-Stegun 7.1.28: |err| <= 3e-7, branch-free.
static __device__ __forceinline__ float erf_fast(float x) {
    float ax = __builtin_fabsf(x);
    float p = fmaf(0.0000430638f, ax, 0.0002765672f);
    p = fmaf(p, ax, 0.0001520143f);
    p = fmaf(p, ax, 0.0092705272f);
    p = fmaf(p, ax, 0.0422820123f);
    p = fmaf(p, ax, 0.0705230784f);
    p = fmaf(p, ax, 1.0f);
    float r = 1.0f / p;
    float r2 = r * r, r4 = r2 * r2, r8 = r4 * r4, r16 = r8 * r8;
    return __builtin_copysignf(1.0f - r16, x);
}

// sum across the 16 lanes of a DPP row, result in every lane of the row.
static __device__ __forceinline__ float sum16(float x) {
    int t;
    t = __builtin_amdgcn_update_dpp(0, __float_as_int(x), 0x128, 0xf, 0xf, false); // row_ror:8
    x += __int_as_float(t);
    t = __builtin_amdgcn_update_dpp(0, __float_as_int(x), 0x124, 0xf, 0xf, false); // row_ror:4
    x += __int_as_float(t);
    t = __builtin_amdgcn_update_dpp(0, __float_as_int(x), 0x122, 0xf, 0xf, false); // row_ror:2
    x += __int_as_float(t);
    t = __builtin_amdgcn_update_dpp(0, __float_as_int(x), 0x121, 0xf, 0xf, false); // row_ror:1
    x += __int_as_float(t);
    return x;
}
// full 64-lane sum, result in every lane.
static __device__ __forceinline__ float sum64_all(float x) {
    x = sum16(x);
    int t = __builtin_amdgcn_ds_swizzle(__float_as_int(x), 0x401F);  // xor 16 (within 32)
    x += __int_as_float(t);
    x += __shfl_xor(x, 32, 64);                                      // xor 32
    return x;
}

// ---------------- fused cast fp32 -> bf16 (x | Wa | Wp, contiguous out) -----
__global__ __launch_bounds__(256) void castall(const float4* __restrict__ x,
                                               const float4* __restrict__ wa,
                                               const float4* __restrict__ wp,
                                               uint2* __restrict__ out) {
    int base = blockIdx.x * 1024 + threadIdx.x;
    #pragma unroll
    for (int k = 0; k < 4; k++) {
        int i = base + k * 256;
        const float4* src;
        int off;
        if (i < 2097152)      { src = x;  off = 0; }
        else if (i < 2883584) { src = wa; off = 2097152; }
        else                  { src = wp; off = 2883584; }
        float4 v = src[i - off];
        uint2 o;
        o.x = (unsigned)f2bf(v.x) | ((unsigned)f2bf(v.y) << 16);
        o.y = (unsigned)f2bf(v.z) | ((unsigned)f2bf(v.w) << 16);
        out[i] = o;
    }
}

// ---------------- GEMM1: qkv = xb @ Wab^T, fused norm+erf -> E --------------
// 256x128 block, 8 waves 4x2, wave tile 64x64 (acc[4][4]). BK=64.
// LDS 48KB single-buffer: As 256x64 (32KB) + Bs 128x64 (16KB).
// Staging: 512 thr x 16B: A 4 rounds of 64 rows, B 2 rounds.
// Swizzle: granule (row r, chunk c) at slot (c+r)&7; thread tid stages
//   chunk ((tid&7)-(tid>>3))&7 of row (tid>>3)+64*round (round-invariant).
// Reads recover chunk quad (half0) / quad+4 (half1) -> identical K order
// to the proven core -> bit-identical numerics. 0 bank conflicts (R1 family).
// E layout: [three][b][h][t][hs], bf16 bits.
__global__ __launch_bounds__(512, 2) void gemm1_qkv_norm(const unsigned short* __restrict__ A,
                                                         const unsigned short* __restrict__ Bm,
                                                         unsigned short* __restrict__ E) {
    __shared__ unsigned short As[256 * 64];   // 32 KB
    __shared__ unsigned short Bs[128 * 64];   // 16 KB
    const int wg = blockIdx.x;                 // 0..767
    const int swz = (wg & 7) * 96 + (wg >> 3); // bijective, 768 % 8 == 0
    const int bx = swz % 24, by = swz / 24;
    const int M0 = by * 256, N0 = bx * 128;
    const int tid = threadIdx.x;               // 0..511
    const int lane = tid & 63, wav = tid >> 6; // wav 0..7
    const int r16 = lane & 15, quad = lane >> 4;
    const int wm = wav >> 1, wn = wav & 1;     // 4 x 2 wave grid
    const int m0 = M0 + wm * 64, n0 = N0 + wn * 64;
    const int rt = tid >> 3;                   // 0..63 (staged row within round)
    const int cc = (tid - rt) & 7;             // staged global chunk
    const unsigned short* pSA = A  + (size_t)(M0 + rt) * 1024 + cc * 8;
    const unsigned short* pSB = Bm + (size_t)(N0 + rt) * 1024 + cc * 8;
    unsigned short* lA0 = As + wav * 512;      // wave-uniform base (+lane*16B HW)
    unsigned short* lB0 = Bs + wav * 512;
    const int fa = wm * 64 + r16;              // 0..255 (A row)
    const int fb = wn * 64 + r16;              // 0..127 (B row)
    const int swa0 = (quad + fa) & 7, swa1 = (swa0 + 4) & 7;
    const int swb0 = (quad + fb) & 7, swb1 = (swb0 + 4) & 7;

    floatx4 acc[4][4];
    #pragma unroll
    for (int i = 0; i < 4; i++)
        #pragma unroll
        for (int j = 0; j < 4; j++) acc[i][j] = (floatx4)0.0f;

    #pragma unroll 1
    for (int ks = 0; ks < 16; ks++) {
        #pragma unroll
        for (int p = 0; p < 4; p++)            // A: 4 rounds x 64 rows
            GLL16(pSA + (size_t)ks * 64 + (size_t)p * 64 * 1024,
                  lA0 + (size_t)p * 4096);
        #pragma unroll
        for (int p = 0; p < 2; p++)            // B: 2 rounds x 64 rows
            GLL16(pSB + (size_t)ks * 64 + (size_t)p * 64 * 1024,
                  lB0 + (size_t)p * 4096);
        __syncthreads();
        short8 af[4], bf[4];
        #pragma unroll
        for (int i = 0; i < 4; i++)
            af[i] = *(const short8*)(As + (fa + i * 16) * 64 + swa0 * 8);
        #pragma unroll
        for (int j = 0; j < 4; j++)
            bf[j] = *(const short8*)(Bs + (fb + j * 16) * 64 + swb0 * 8);
        #pragma unroll
        for (int i = 0; i < 4; i++)
            #pragma unroll
            for (int j = 0; j < 4; j++)
                acc[i][j] = __builtin_amdgcn_mfma_f32_16x16x32_bf16(
                    af[i], bf[j], acc[i][j], 0, 0, 0);
        #pragma unroll
        for (int i = 0; i < 4; i++)
            af[i] = *(const short8*)(As + (fa + i * 16) * 64 + swa1 * 8);
        #pragma unroll
        for (int j = 0; j < 4; j++)
            bf[j] = *(const short8*)(Bs + (fb + j * 16) * 64 + swb1 * 8);
        #pragma unroll
        for (int i = 0; i < 4; i++)
            #pragma unroll
            for (int j = 0; j < 4; j++)
                acc[i][j] = __builtin_amdgcn_mfma_f32_16x16x32_bf16(
                    af[i], bf[j], acc[i][j], 0, 0, 0);
        __syncthreads();
    }

    // fused per-64-group normalization: this wave's 64-col tile == one (three,h)
    int gcol  = n0 >> 6;            // 0..47
    int three = gcol >> 4, h = gcol & 15;
    #pragma unroll
    for (int i = 0; i < 4; i++) {
        #pragma unroll
        for (int r = 0; r < 4; r++) {
            float s = 0.f, ss = 0.f;
            #pragma unroll
            for (int j = 0; j < 4; j++) { float v = acc[i][j][r]; s += v; ss += v * v; }
            s = sum16(s); ss = sum16(ss);
            float mean = s * (1.0f / 64.0f);
            float var  = (ss - s * s * (1.0f / 64.0f)) * (1.0f / 63.0f);  // ddof=1
            float rstd = rsqrtf(var);
            int rowm = m0 + i * 16 + quad * 4 + r;     // = b*2048 + t
            int bb = rowm >> 11, tt2 = rowm & 2047;
            size_t base = ((((size_t)three * 4 + bb) * 16 + h) * 2048 + tt2) * 64;
            #pragma unroll
            for (int j = 0; j < 4; j++) {
                float v = (acc[i][j][r] - mean) * rstd;
                if (three < 2) v = erf_fast(v);
                E[base + j * 16 + r16] = f2bf(v);
            }
        }
    }
}

// ---------------- GEMM2: out = x + vt @ Wp^T (fp32 out) ---------------------
// 128x128 block tile, 4 waves 2x2, wave tile 64x64 (acc[4][4]).
// BK=128 double-stage (8 barrier pairs), 64KB LDS, 2 blocks/CU, XCD swizzle.
// (R7-proven configuration, unchanged.)
__global__ __launch_bounds__(256, 2) void gemm2_proj_add(const unsigned short* __restrict__ A,
                                                         const unsigned short* __restrict__ Bm,
                                                         const float* __restrict__ X,
                                                         float* __restrict__ Out) {
    __shared__ unsigned short As[2 * 128 * 64];   // 32 KB
    __shared__ unsigned short Bs[2 * 128 * 64];   // 32 KB
    const int wg = blockIdx.x;                 // 0..511
    const int swz = (wg & 7) * 64 + (wg >> 3); // bijective, 512 % 8 == 0
    const int bx = swz & 7, by = swz >> 3;
    const int tid = threadIdx.x;
    const int lane = tid & 63, wav = tid >> 6;
    const int r16 = lane & 15, quad = lane >> 4;
    const int M0 = by * 128, N0 = bx * 128;
    const int wm = wav >> 1, wn = wav & 1;
    const int m0 = M0 + wm * 64, n0 = N0 + wn * 64;
    const int rr0 = tid >> 3;                      // 0..31
    const int cc0 = (tid - rr0) & 7;
    const unsigned short* pA0 = A  + (size_t)(M0 + rr0) * 1024 + cc0 * 8;
    const unsigned short* pB0 = Bm + (size_t)(N0 + rr0) * 1024 + cc0 * 8;
    unsigned short* lA0 = As + (size_t)(wav * 64) * 8;
    unsigned short* lB0 = Bs + (size_t)(wav * 64) * 8;
    const int fa = wm * 64 + r16, fb = wn * 64 + r16;
    const int swa0 = (quad + fa) & 7, swa1 = (swa0 + 4) & 7;
    const int swb0 = (quad + fb) & 7, swb1 = (swb0 + 4) & 7;
    floatx4 acc[4][4];
    #pragma unroll
    for (int i = 0; i < 4; i++)
        #pragma unroll
        for (int j = 0; j < 4; j++) acc[i][j] = (floatx4)0.0f;

    #pragma unroll 1
    for (int ks = 0; ks < 8; ks++) {               // 8 x BK=128 supersteps
        #pragma unroll
        for (int kh = 0; kh < 2; kh++) {           // two 64-K halves
            #pragma unroll
            for (int p = 0; p < 4; p++)
                GLL16(pA0 + (size_t)ks * 128 + kh * 64 + (size_t)p * 32 * 1024,
                      lA0 + kh * 8192 + (size_t)p * 2048);
            #pragma unroll
            for (int p = 0; p < 4; p++)
                GLL16(pB0 + (size_t)ks * 128 + kh * 64 + (size_t)p * 32 * 1024,
                      lB0 + kh * 8192 + (size_t)p * 2048);
        }
        __syncthreads();
        #pragma unroll
        for (int kh = 0; kh < 2; kh++) {
            const unsigned short* Ah = As + kh * 8192;
            const unsigned short* Bh = Bs + kh * 8192;
            short8 af[4], bf[4];
            #pragma unroll
            for (int i = 0; i < 4; i++)
                af[i] = *(const short8*)(Ah + (fa + i * 16) * 64 + swa0 * 8);
            #pragma unroll
            for (int j = 0; j < 4; j++)
                bf[j] = *(const short8*)(Bh + (fb + j * 16) * 64 + swb0 * 8);
            #pragma unroll
            for (int i = 0; i < 4; i++)
                #pragma unroll
                for (int j = 0; j < 4; j++)
                    acc[i][j] = __builtin_amdgcn_mfma_f32_16x16x32_bf16(
                        af[i], bf[j], acc[i][j], 0, 0, 0);
            #pragma unroll
            for (int i = 0; i < 4; i++)
                af[i] = *(const short8*)(Ah + (fa + i * 16) * 64 + swa1 * 8);
            #pragma unroll
            for (int j = 0; j < 4; j++)
                bf[j] = *(const short8*)(Bh + (fb + j * 16) * 64 + swb1 * 8);
            #pragma unroll
            for (int i = 0; i < 4; i++)
                #pragma unroll
                for (int j = 0; j < 4; j++)
                    acc[i][j] = __builtin_amdgcn_mfma_f32_16x16x32_bf16(
                        af[i], bf[j], acc[i][j], 0, 0, 0);
        }
        __syncthreads();
    }

    #pragma unroll
    for (int i = 0; i < 4; i++)
        #pragma unroll
        for (int j = 0; j < 4; j++)
            #pragma unroll
            for (int r = 0; r < 4; r++) {
                size_t idx = (size_t)(m0 + i * 16 + quad * 4 + r) * 1024 + (n0 + j * 16 + r16);
                Out[idx] = acc[i][j][r] + X[idx];
            }
}

// ---------------- rolling chunked scan -> vt --------------------------------
// Exact recursion carried in registers: sv_t = v_t - G_t * sv_{t-1},
//   G_t = k~_{t-1}.k_t ; vt_t[i] = H0 sv_t[i] + w_i H1 sv_{t-1}[i].
// One wave per (b,h,chunk-of-16): 64 x 128 = 8192 waves = 2048 blocks.
__global__ __launch_bounds__(256) void band_vt(const unsigned short* __restrict__ E,
                                               const float* __restrict__ w,
                                               const float* __restrict__ eta,
                                               unsigned short* __restrict__ vt) {
    const int lane = threadIdx.x & 63;
    const int wav  = threadIdx.x >> 6;
    const int gid  = blockIdx.x * 4 + wav;        // 0..8191
    const int chunk = gid & 127;                  // 128 chunks of 16 t
    const int p     = gid >> 7;                   // (b,h): 0..63
    const int b = p >> 4, h = p & 15;
    const int t0 = chunk * 16;

    const size_t PL = (size_t)4 * 16 * 2048 * 64;               // one "three" plane
    const size_t pbh = ((size_t)b * 16 + h) * (2048 * 64);
    const unsigned short* qb = E + pbh;
    const unsigned short* kb = E + PL + pbh;
    const unsigned short* vb = E + 2 * PL + pbh;

    const float e  = eta[h * 64 + lane];
    const float wi = w[h * 64 + lane];

    // ---- warm-up: rolling kh_{t0-1} and seeded sv_{t0-1} (wave-uniform guards)
    float kh_p, sv_p;
    if (t0 == 0) {
        kh_p = 0.f;
        sv_p = 0.f;
    } else {
        float k1 = bflo(kb[(size_t)(t0 - 1) * 64 + lane]);
        float k2 = bflo(kb[(size_t)(t0 - 2) * 64 + lane]);
        float k3 = bflo(kb[(size_t)(t0 - 3) * 64 + lane]);
        float v1 = bflo(vb[(size_t)(t0 - 1) * 64 + lane]);
        float v2 = bflo(vb[(size_t)(t0 - 2) * 64 + lane]);
        float v3 = bflo(vb[(size_t)(t0 - 3) * 64 + lane]);
        float G1 = sum64_all((k2 * e) * k1);      // G_{t0-1} = k~_{t0-2}.k_{t0-1}
        float G2 = sum64_all((k3 * e) * k2);      // G_{t0-2} = k~_{t0-3}.k_{t0-2}
        sv_p = v1 - G1 * (v2 - G2 * v3);          // sv_{t0-1}, 3-term seed
        kh_p = k1 * e;
    }

    const unsigned short* pq = qb + (size_t)t0 * 64 + lane;
    const unsigned short* pk = kb + (size_t)t0 * 64 + lane;
    const unsigned short* pv = vb + (size_t)t0 * 64 + lane;
    unsigned short* po = vt + ((size_t)b * 2048 + t0) * 1024 + h * 64 + lane;

    #pragma unroll
    for (int tt = 0; tt < 16; tt++) {
        float qt = bflo(pq[tt * 64]);
        float kt = bflo(pk[tt * 64]);
        float vv = bflo(pv[tt * 64]);
        float kh = kt * e;
        float Gt = sum64_all(kh_p * kt);          // k~_{t-1}.k_t
        float H0 = sum64_all(kh * qt);            // k~_t.q_t
        float H1 = sum64_all(kh_p * qt);          // k~_{t-1}.q_t
        float sv = fmaf(-Gt, sv_p, vv);           // sv_t = v_t - G_t sv_{t-1}
        float r  = fmaf(H0, sv, wi * (H1 * sv_p));
        po[(size_t)tt * 1024] = f2bf(r);
        kh_p = kh;
        sv_p = sv;
    }
}

// ---------------------------------------------------------------------------
extern "C" void kernel_launch(void* const* d_in, const int* in_sizes, int n_in,
                              void* d_out, int out_size, void* d_ws, size_t ws_size,
                              hipStream_t stream) {
    const float* x   = (const float*)d_in[0];   // (4,2048,1024)
    const float* Wa  = (const float*)d_in[1];   // (3072,1024)
    const float* Wp  = (const float*)d_in[2];   // (1024,1024)
    const float* w   = (const float*)d_in[3];   // (1024,)
    const float* eta = (const float*)d_in[4];   // (1024,)
    float* out = (float*)d_out;

    char* ws = (char*)d_ws;
    unsigned short* xb  = (unsigned short*)(ws + 0);          // 16777216 B
    unsigned short* Wab = (unsigned short*)(ws + 16777216);   //  6291456 B
    unsigned short* Wpb = (unsigned short*)(ws + 23068672);   //  2097152 B
    unsigned short* E   = (unsigned short*)(ws + 25165824);   // 50331648 B
    unsigned short* vtb = (unsigned short*)(ws + 75497728);   // 16777216 B  -> end 92274944

    castall<<<3072, 256, 0, stream>>>((const float4*)x, (const float4*)Wa,
                                      (const float4*)Wp, (uint2*)xb);

    gemm1_qkv_norm<<<768, 512, 0, stream>>>(xb, Wab, E);
    band_vt<<<2048, 256, 0, stream>>>(E, w, eta, vtb);
    gemm2_proj_add<<<512, 256, 0, stream>>>(vtb, Wpb, x, out);
}

// Round 11
// 194.679 us; speedup vs baseline: 1.0863x; 1.0252x over previous
//
#include <hip/hip_runtime.h>
#include <math.h>

// ---------------------------------------------------------------------------
// RWKV7-ish CausalSelfAttention, MI355X gfx950.
// B=4 T=2048 C=1024 NH=16 HS=64.
// Pipeline: castall v2 (ILP-4) -> bf16 ;
//   GEMM1: proven 4-wave 256x128 core (128x64 wave tiles, BK=64, GLL16 +
//          swizzled LDS, 2-barrier, XCD swizzle) + fused groupnorm/erf -> E ;
//   band_vt rolling chunked scan -> vt ;
//   GEMM2 v3: 128x128 block, 4 waves K-SPLIT (wk,wn): each wave a 128x64
//          PARTIAL over half of each BK=128 supertile (acc[8][4] = gemm1's
//          proven intensity 24KB-read/64MFMA), 16-slot swizzle, 64KB LDS,
//          LDS fp32 reduction epilogue + residual. Grid 512 = 2 blk/CU.
// R10 lesson (quantified): 64x64 wave tiles double LDS-read per MFMA ->
//   port-bound (MfmaUtil 21%). 128x64 is the balance point; gemm2's old
//   64x64 config is the last place that ratio survives -> K-split fixes it
//   while keeping grid fill. One fp32 reassociation (~1e-5 << 0.0156 floor).
// Workspace: xb 16MB | Wab 6MB | Wpb 2MB | E 48MB | vt 16MB = 88MiB
// ---------------------------------------------------------------------------

typedef __attribute__((ext_vector_type(8))) short short8;     // 8 x bf16 bits
typedef __attribute__((ext_vector_type(4))) float floatx4;

#define GLL16(g, l)                                                            \
    __builtin_amdgcn_global_load_lds(                                          \
        (const __attribute__((address_space(1))) void*)(g),                    \
        (__attribute__((address_space(3))) void*)(l), 16, 0, 0)

static __device__ __forceinline__ unsigned short f2bf(float f) {
    unsigned u = __float_as_uint(f);
    unsigned r = (u + 0x7fffu + ((u >> 16) & 1u)) >> 16;
    return (unsigned short)r;
}
static __device__ __forceinline__ float bflo(unsigned v) { return __uint_as_float(v << 16); }

// Abramowitz-Stegun 7.1.28: |err| <= 3e-7, branch-free.
static __device__ __forceinline__ float erf_fast(float x) {
    float ax = __builtin_fabsf(x);
    float p = fmaf(0.0000430638f, ax, 0.0002765672f);
    p = fmaf(p, ax, 0.0001520143f);
    p = fmaf(p, ax, 0.0092705272f);
    p = fmaf(p, ax, 0.0422820123f);
    p = fmaf(p, ax, 0.0705230784f);
    p = fmaf(p, ax, 1.0f);
    float r = 1.0f / p;
    float r2 = r * r, r4 = r2 * r2, r8 = r4 * r4, r16 = r8 * r8;
    return __builtin_copysignf(1.0f - r16, x);
}

// sum across the 16 lanes of a DPP row, result in every lane of the row.
static __device__ __forceinline__ float sum16(float x) {
    int t;
    t = __builtin_amdgcn_update_dpp(0, __float_as_int(x), 0x128, 0xf, 0xf, false); // row_ror:8
    x += __int_as_float(t);
    t = __builtin_amdgcn_update_dpp(0, __float_as_int(x), 0x124, 0xf, 0xf, false); // row_ror:4
    x += __int_as_float(t);
    t = __builtin_amdgcn_update_dpp(0, __float_as_int(x), 0x122, 0xf, 0xf, false); // row_ror:2
    x += __int_as_float(t);
    t = __builtin_amdgcn_update_dpp(0, __float_as_int(x), 0x121, 0xf, 0xf, false); // row_ror:1
    x += __int_as_float(t);
    return x;
}
// full 64-lane sum, result in every lane.
static __device__ __forceinline__ float sum64_all(float x) {
    x = sum16(x);
    int t = __builtin_amdgcn_ds_swizzle(__float_as_int(x), 0x401F);  // xor 16 (within 32)
    x += __int_as_float(t);
    x += __shfl_xor(x, 32, 64);                                      // xor 32
    return x;
}

// ---------------- fused cast fp32 -> bf16 (x | Wa | Wp, contiguous out) -----
__global__ __launch_bounds__(256) void castall(const float4* __restrict__ x,
                                               const float4* __restrict__ wa,
                                               const float4* __restrict__ wp,
                                               uint2* __restrict__ out) {
    int base = blockIdx.x * 1024 + threadIdx.x;
    #pragma unroll
    for (int k = 0; k < 4; k++) {
        int i = base + k * 256;
        const float4* src;
        int off;
        if (i < 2097152)      { src = x;  off = 0; }
        else if (i < 2883584) { src = wa; off = 2097152; }
        else                  { src = wp; off = 2883584; }
        float4 v = src[i - off];
        uint2 o;
        o.x = (unsigned)f2bf(v.x) | ((unsigned)f2bf(v.y) << 16);
        o.y = (unsigned)f2bf(v.z) | ((unsigned)f2bf(v.w) << 16);
        out[i] = o;
    }
}

// ---------------------------------------------------------------------------
// GEMM core (proven), C = A @ B^T. Block 256x128, 4 waves 2x2, wave tile
// 128x64 (acc[8][4]), BK=64, GLL16 staging, swizzled LDS (0 conflicts).
// ---------------------------------------------------------------------------
#define GEMM_CORE_BIG(A_, B_, Kc, M0_, N0_)                                    \
    __shared__ unsigned short As[256 * 64];   /* 32 KB */                      \
    __shared__ unsigned short Bs[128 * 64];   /* 16 KB */                      \
    const int tid = threadIdx.x;                                               \
    const int lane = tid & 63, wav = tid >> 6;                                 \
    const int r16 = lane & 15, quad = lane >> 4;                               \
    const int M0 = (M0_), N0 = (N0_);                                          \
    const int wm = wav >> 1, wn = wav & 1;                                     \
    const int m0 = M0 + wm * 128, n0 = N0 + wn * 64;                           \
    const int rr0 = tid >> 3;                                                  \
    const int cc0 = (tid - rr0) & 7;                                           \
    const unsigned short* pA0 = A_ + (size_t)(M0 + rr0) * Kc + cc0 * 8;        \
    const unsigned short* pB0 = B_ + (size_t)(N0 + rr0) * Kc + cc0 * 8;        \
    unsigned short* lA0 = As + (size_t)(wav * 64) * 8;                         \
    unsigned short* lB0 = Bs + (size_t)(wav * 64) * 8;                         \
    const int fa = wm * 128 + r16, fb = wn * 64 + r16;                         \
    const int swa0 = (quad + fa) & 7, swa1 = (swa0 + 4) & 7;                   \
    const int swb0 = (quad + fb) & 7, swb1 = (swb0 + 4) & 7;                   \
    floatx4 acc[8][4];                                                         \
    _Pragma("unroll") for (int i = 0; i < 8; i++)                              \
        _Pragma("unroll") for (int j = 0; j < 4; j++) acc[i][j] = (floatx4)0.0f; \
    _Pragma("unroll 1") for (int ks = 0; ks < (Kc / 64); ks++) {               \
        _Pragma("unroll") for (int p = 0; p < 8; p++)                          \
            GLL16(pA0 + (size_t)ks * 64 + (size_t)p * 32 * Kc,                 \
                  lA0 + (size_t)p * 2048);                                     \
        _Pragma("unroll") for (int p = 0; p < 4; p++)                          \
            GLL16(pB0 + (size_t)ks * 64 + (size_t)p * 32 * Kc,                 \
                  lB0 + (size_t)p * 2048);                                     \
        __syncthreads();                                                       \
        short8 af[8], bf[4];                                                   \
        _Pragma("unroll") for (int i = 0; i < 8; i++)                          \
            af[i] = *(const short8*)(As + (fa + i * 16) * 64 + swa0 * 8);      \
        _Pragma("unroll") for (int j = 0; j < 4; j++)                          \
            bf[j] = *(const short8*)(Bs + (fb + j * 16) * 64 + swb0 * 8);      \
        _Pragma("unroll") for (int i = 0; i < 8; i++)                          \
            _Pragma("unroll") for (int j = 0; j < 4; j++)                      \
                acc[i][j] = __builtin_amdgcn_mfma_f32_16x16x32_bf16(           \
                    af[i], bf[j], acc[i][j], 0, 0, 0);                         \
        _Pragma("unroll") for (int i = 0; i < 8; i++)                          \
            af[i] = *(const short8*)(As + (fa + i * 16) * 64 + swa1 * 8);      \
        _Pragma("unroll") for (int j = 0; j < 4; j++)                          \
            bf[j] = *(const short8*)(Bs + (fb + j * 16) * 64 + swb1 * 8);      \
        _Pragma("unroll") for (int i = 0; i < 8; i++)                          \
            _Pragma("unroll") for (int j = 0; j < 4; j++)                      \
                acc[i][j] = __builtin_amdgcn_mfma_f32_16x16x32_bf16(           \
                    af[i], bf[j], acc[i][j], 0, 0, 0);                         \
        __syncthreads();                                                       \
    }

// ---------------- GEMM1: qkv = xb @ Wab^T, fused norm+erf -> E --------------
// 1-D grid 768, XCD-bijective swizzle, 2 blocks/CU (register-bound: 212 regs).
// E layout: [three][b][h][t][hs], bf16 bits.
__global__ __launch_bounds__(256, 2) void gemm1_qkv_norm(const unsigned short* __restrict__ A,
                                                         const unsigned short* __restrict__ Bm,
                                                         unsigned short* __restrict__ E) {
    const int wg = blockIdx.x;                 // 0..767
    const int swz = (wg & 7) * 96 + (wg >> 3); // bijective, 768 % 8 == 0
    const int bx = swz % 24, by = swz / 24;
    GEMM_CORE_BIG(A, Bm, 1024, by * 256, bx * 128)

    // fused per-64-group normalization: this wave's 64-col tile == one (three,h)
    int gcol  = n0 >> 6;            // 0..47
    int three = gcol >> 4, h = gcol & 15;
    #pragma unroll
    for (int i = 0; i < 8; i++) {
        #pragma unroll
        for (int r = 0; r < 4; r++) {
            float s = 0.f, ss = 0.f;
            #pragma unroll
            for (int j = 0; j < 4; j++) { float v = acc[i][j][r]; s += v; ss += v * v; }
            s = sum16(s); ss = sum16(ss);
            float mean = s * (1.0f / 64.0f);
            float var  = (ss - s * s * (1.0f / 64.0f)) * (1.0f / 63.0f);  // ddof=1
            float rstd = rsqrtf(var);
            int rowm = m0 + i * 16 + quad * 4 + r;     // = b*2048 + t
            int bb = rowm >> 11, tt2 = rowm & 2047;
            size_t base = ((((size_t)three * 4 + bb) * 16 + h) * 2048 + tt2) * 64;
            #pragma unroll
            for (int j = 0; j < 4; j++) {
                float v = (acc[i][j][r] - mean) * rstd;
                if (three < 2) v = erf_fast(v);
                E[base + j * 16 + r16] = f2bf(v);
            }
        }
    }
}

// ---------------- GEMM2 v3: out = x + vt @ Wp^T (fp32 out), K-split ---------
// Block 128(M)x128(N), BK=128 supertile, 4 waves (wk = K-half, wn = N-half).
// Wave (wk,wn): 128x64 partial over chunks [wk*8, wk*8+8) of each supertile,
// acc[8][4] -- gemm1's proven intensity. 16-slot swizzle: granule (row r,
// chunk c) at slot (c+r)&15; staging linear in tid (rr=tid>>4, cc=
// ((tid&15)-rr)&15); read slot (wk*8+quad+r16)&15 recovers chunk wk*8+quad
// (+4 for half1) -> sequential K within wave. Epilogue: wk=1 stores fp32
// partial to LDS (64KB reuse), wk=0 adds + X residual. One reassociation.
__global__ __launch_bounds__(256, 2) void gemm2_proj_add(const unsigned short* __restrict__ A,
                                                         const unsigned short* __restrict__ Bm,
                                                         const float* __restrict__ X,
                                                         float* __restrict__ Out) {
    __shared__ unsigned short L[32768];        // 64 KB: A 32KB | B 32KB
    unsigned short* LB = L + 16384;
    const int wg = blockIdx.x;                 // 0..511
    const int swz = (wg & 7) * 64 + (wg >> 3); // bijective, 512 % 8 == 0
    const int bx = swz & 7, by = swz >> 3;
    const int tid = threadIdx.x;
    const int lane = tid & 63, wav = tid >> 6;
    const int r16 = lane & 15, quad = lane >> 4;
    const int M0 = by * 128, N0 = bx * 128;
    const int wk = wav >> 1, wn = wav & 1;
    const int n0 = N0 + wn * 64;
    const int rr = tid >> 4;                   // 0..15 (staged row within round)
    const int cc = ((tid & 15) - rr) & 15;     // staged chunk (16B granule)
    const unsigned short* pSA = A  + (size_t)(M0 + rr) * 1024 + cc * 8;
    const unsigned short* pSB = Bm + (size_t)(N0 + rr) * 1024 + cc * 8;
    unsigned short* lA0 = L  + wav * 512;      // wave-uniform + lane*16B
    unsigned short* lB0 = LB + wav * 512;
    const int slot = (wk * 8 + quad + r16) & 15;            // read slot, half0
    const int slot1 = (wk * 8 + quad + 4 + r16) & 15;       // half1

    floatx4 acc[8][4];
    #pragma unroll
    for (int i = 0; i < 8; i++)
        #pragma unroll
        for (int j = 0; j < 4; j++) acc[i][j] = (floatx4)0.0f;

    #pragma unroll 1
    for (int ks = 0; ks < 8; ks++) {           // 8 x BK=128 supertiles
        #pragma unroll
        for (int p = 0; p < 8; p++)            // A: 8 rounds x 16 rows
            GLL16(pSA + (size_t)ks * 128 + (size_t)p * 16 * 1024,
                  lA0 + (size_t)p * 2048);
        #pragma unroll
        for (int p = 0; p < 8; p++)            // B: 8 rounds x 16 rows
            GLL16(pSB + (size_t)ks * 128 + (size_t)p * 16 * 1024,
                  lB0 + (size_t)p * 2048);
        __syncthreads();
        short8 af[8], bf[4];
        #pragma unroll
        for (int i = 0; i < 8; i++)            // rows r16 + i*16 (0..127)
            af[i] = *(const short8*)(L + (r16 + i * 16) * 128 + slot * 8);
        #pragma unroll
        for (int j = 0; j < 4; j++)            // rows wn*64 + r16 + j*16
            bf[j] = *(const short8*)(LB + (wn * 64 + r16 + j * 16) * 128 + slot * 8);
        #pragma unroll
        for (int i = 0; i < 8; i++)
            #pragma unroll
            for (int j = 0; j < 4; j++)
                acc[i][j] = __builtin_amdgcn_mfma_f32_16x16x32_bf16(
                    af[i], bf[j], acc[i][j], 0, 0, 0);
        #pragma unroll
        for (int i = 0; i < 8; i++)
            af[i] = *(const short8*)(L + (r16 + i * 16) * 128 + slot1 * 8);
        #pragma unroll
        for (int j = 0; j < 4; j++)
            bf[j] = *(const short8*)(LB + (wn * 64 + r16 + j * 16) * 128 + slot1 * 8);
        #pragma unroll
        for (int i = 0; i < 8; i++)
            #pragma unroll
            for (int j = 0; j < 4; j++)
                acc[i][j] = __builtin_amdgcn_mfma_f32_16x16x32_bf16(
                    af[i], bf[j], acc[i][j], 0, 0, 0);
        __syncthreads();
    }

    // ---- K-split reduction: wk=1 partial -> LDS (fp32), wk=0 adds + residual
    float* Lf = (float*)L;                     // 16384 floats = 64 KB
    if (wk == 1) {
        #pragma unroll
        for (int i = 0; i < 8; i++)
            #pragma unroll
            for (int j = 0; j < 4; j++)
                #pragma unroll
                for (int r = 0; r < 4; r++)
                    Lf[wn * 8192 + (i * 16 + quad * 4 + r) * 64 + j * 16 + r16] =
                        acc[i][j][r];
    }
    __syncthreads();
    if (wk == 0) {
        #pragma unroll
        for (int i = 0; i < 8; i++)
            #pragma unroll
            for (int j = 0; j < 4; j++)
                #pragma unroll
                for (int r = 0; r < 4; r++) {
                    int row = i * 16 + quad * 4 + r, col = j * 16 + r16;
                    float v = acc[i][j][r] + Lf[wn * 8192 + row * 64 + col];
                    size_t idx = (size_t)(M0 + row) * 1024 + n0 + col;
                    Out[idx] = v + X[idx];
                }
    }
}

// ---------------- rolling chunked scan -> vt --------------------------------
// Exact recursion carried in registers: sv_t = v_t - G_t * sv_{t-1},
//   G_t = k~_{t-1}.k_t ; vt_t[i] = H0 sv_t[i] + w_i H1 sv_{t-1}[i].
// One wave per (b,h,chunk-of-16): 64 x 128 = 8192 waves = 2048 blocks.
__global__ __launch_bounds__(256) void band_vt(const unsigned short* __restrict__ E,
                                               const float* __restrict__ w,
                                               const float* __restrict__ eta,
                                               unsigned short* __restrict__ vt) {
    const int lane = threadIdx.x & 63;
    const int wav  = threadIdx.x >> 6;
    const int gid  = blockIdx.x * 4 + wav;        // 0..8191
    const int chunk = gid & 127;                  // 128 chunks of 16 t
    const int p     = gid >> 7;                   // (b,h): 0..63
    const int b = p >> 4, h = p & 15;
    const int t0 = chunk * 16;

    const size_t PL = (size_t)4 * 16 * 2048 * 64;               // one "three" plane
    const size_t pbh = ((size_t)b * 16 + h) * (2048 * 64);
    const unsigned short* qb = E + pbh;
    const unsigned short* kb = E + PL + pbh;
    const unsigned short* vb = E + 2 * PL + pbh;

    const float e  = eta[h * 64 + lane];
    const float wi = w[h * 64 + lane];

    // ---- warm-up: rolling kh_{t0-1} and seeded sv_{t0-1} (wave-uniform guards)
    float kh_p, sv_p;
    if (t0 == 0) {
        kh_p = 0.f;
        sv_p = 0.f;
    } else {
        float k1 = bflo(kb[(size_t)(t0 - 1) * 64 + lane]);
        float k2 = bflo(kb[(size_t)(t0 - 2) * 64 + lane]);
        float k3 = bflo(kb[(size_t)(t0 - 3) * 64 + lane]);
        float v1 = bflo(vb[(size_t)(t0 - 1) * 64 + lane]);
        float v2 = bflo(vb[(size_t)(t0 - 2) * 64 + lane]);
        float v3 = bflo(vb[(size_t)(t0 - 3) * 64 + lane]);
        float G1 = sum64_all((k2 * e) * k1);      // G_{t0-1} = k~_{t0-2}.k_{t0-1}
        float G2 = sum64_all((k3 * e) * k2);      // G_{t0-2} = k~_{t0-3}.k_{t0-2}
        sv_p = v1 - G1 * (v2 - G2 * v3);          // sv_{t0-1}, 3-term seed
        kh_p = k1 * e;
    }

    const unsigned short* pq = qb + (size_t)t0 * 64 + lane;
    const unsigned short* pk = kb + (size_t)t0 * 64 + lane;
    const unsigned short* pv = vb + (size_t)t0 * 64 + lane;
    unsigned short* po = vt + ((size_t)b * 2048 + t0) * 1024 + h * 64 + lane;

    #pragma unroll
    for (int tt = 0; tt < 16; tt++) {
        float qt = bflo(pq[tt * 64]);
        float kt = bflo(pk[tt * 64]);
        float vv = bflo(pv[tt * 64]);
        float kh = kt * e;
        float Gt = sum64_all(kh_p * kt);          // k~_{t-1}.k_t
        float H0 = sum64_all(kh * qt);            // k~_t.q_t
        float H1 = sum64_all(kh_p * qt);          // k~_{t-1}.q_t
        float sv = fmaf(-Gt, sv_p, vv);           // sv_t = v_t - G_t sv_{t-1}
        float r  = fmaf(H0, sv, wi * (H1 * sv_p));
        po[(size_t)tt * 1024] = f2bf(r);
        kh_p = kh;
        sv_p = sv;
    }
}

// ---------------------------------------------------------------------------
extern "C" void kernel_launch(void* const* d_in, const int* in_sizes, int n_in,
                              void* d_out, int out_size, void* d_ws, size_t ws_size,
                              hipStream_t stream) {
    const float* x   = (const float*)d_in[0];   // (4,2048,1024)
    const float* Wa  = (const float*)d_in[1];   // (3072,1024)
    const float* Wp  = (const float*)d_in[2];   // (1024,1024)
    const float* w   = (const float*)d_in[3];   // (1024,)
    const float* eta = (const float*)d_in[4];   // (1024,)
    float* out = (float*)d_out;

    char* ws = (char*)d_ws;
    unsigned short* xb  = (unsigned short*)(ws + 0);          // 16777216 B
    unsigned short* Wab = (unsigned short*)(ws + 16777216);   //  6291456 B
    unsigned short* Wpb = (unsigned short*)(ws + 23068672);   //  2097152 B
    unsigned short* E   = (unsigned short*)(ws + 25165824);   // 50331648 B
    unsigned short* vtb = (unsigned short*)(ws + 75497728);   // 16777216 B  -> end 92274944

    castall<<<3072, 256, 0, stream>>>((const float4*)x, (const float4*)Wa,
                                      (const float4*)Wp, (uint2*)xb);

    gemm1_qkv_norm<<<768, 256, 0, stream>>>(xb, Wab, E);
    band_vt<<<2048, 256, 0, stream>>>(E, w, eta, vtb);
    gemm2_proj_add<<<512, 256, 0, stream>>>(vtb, Wpb, x, out);
}